// Round 4
// baseline (515.656 us; speedup 1.0000x reference)
//
#include <hip/hip_runtime.h>
#include <hip/hip_bf16.h>

#define NB  32
#define NTQ 1024
#define NTV 1024
#define ND  512

typedef float f32x4 __attribute__((ext_vector_type(4)));
typedef float f32x2 __attribute__((ext_vector_type(2)));
typedef __bf16 bf16x8 __attribute__((ext_vector_type(8)));
typedef unsigned short u16x4 __attribute__((ext_vector_type(4)));
typedef unsigned short u16x8 __attribute__((ext_vector_type(8)));
typedef unsigned int u32x2 __attribute__((ext_vector_type(2)));
typedef unsigned int u32x4 __attribute__((ext_vector_type(4)));

static __device__ __forceinline__ unsigned short f2bf(float f) {   // RTN-even
  unsigned u = __builtin_bit_cast(unsigned, f);
  u += 0x7fffu + ((u >> 16) & 1u);
  return (unsigned short)(u >> 16);
}
static __device__ __forceinline__ float bf2f(unsigned short h) {
  unsigned u = ((unsigned)h) << 16;
  return __builtin_bit_cast(float, u);
}
// trunc split: packed (hi | lo<<16)
static __device__ __forceinline__ unsigned split2(float x) {
  unsigned u = __builtin_bit_cast(unsigned, x);
  unsigned h = u >> 16;
  float hf = __builtin_bit_cast(float, u & 0xffff0000u);
  unsigned l = __builtin_bit_cast(unsigned, x - hf) >> 16;
  return h | (l << 16);
}
static __device__ __forceinline__ f32x4 mfma16(bf16x8 a, bf16x8 b, f32x4 c) {
  return __builtin_amdgcn_mfma_f32_16x16x32_bf16(a, b, c, 0, 0, 0);
}

// ---------------- kernel 0: V [B,TV,D] f32 -> Vt [B,D,TV] bf16 ----------------
__global__ __launch_bounds__(256) void k_vt(const float* __restrict__ V,
                                            unsigned short* __restrict__ Vt) {
  int vt = blockIdx.x, dt = blockIdx.y, b = blockIdx.z;
  int t = threadIdx.x;
  __shared__ unsigned short L[64][72];
#pragma unroll
  for (int r = 0; r < 4; ++r) {
    int v = (t >> 4) + r * 16;
    int c4 = (t & 15) * 4;
    f32x4 x = *(const f32x4*)(V + (size_t)(b * NTV + vt * 64 + v) * ND + dt * 64 + c4);
    u16x4 h;
#pragma unroll
    for (int j = 0; j < 4; ++j) h[j] = f2bf(x[j]);
    *(u16x4*)&L[v][c4] = h;
  }
  __syncthreads();
#pragma unroll
  for (int r = 0; r < 4; ++r) {
    int d = (t >> 4) + r * 16;
    int v4 = (t & 15) * 4;
    u16x4 o;
#pragma unroll
    for (int i = 0; i < 4; ++i) o[i] = L[v4 + i][d];
    *(u16x4*)(Vt + (size_t)(b * ND + dt * 64 + d) * NTV + vt * 64 + v4) = o;
  }
}

// ------- kernel 1: keys = V @ W^T + bias, trunc-split, reg-prefetch pipeline -------
__global__ __launch_bounds__(256, 2) void k_keys(const float* __restrict__ V,
                                                 const float* __restrict__ W,
                                                 const float* __restrict__ bias,
                                                 unsigned int* __restrict__ kbuf) {
  int bid = blockIdx.x;
  int swz = (bid & 7) * 128 + (bid >> 3);
  int bm = swz >> 2, bn = swz & 3;
  int t = threadIdx.x, lane = t & 63, w = t >> 6;
  int wr = (w >> 1) * 64, wc = (w & 1) * 64;
  __shared__ __align__(16) unsigned char SMEM[73728];
  auto Ah = (unsigned short(*)[72])(SMEM);
  auto Al = (unsigned short(*)[72])(SMEM + 18432);
  auto Bh = (unsigned short(*)[72])(SMEM + 36864);
  auto Bl = (unsigned short(*)[72])(SMEM + 55296);
  f32x4 acc[4][4] = {};
  const int row0 = bm * 128, col0 = bn * 128;
  int srow = t >> 4, c4 = (t & 15) * 4;

  f32x4 vreg[8], wreg[8];
#pragma unroll
  for (int r = 0; r < 8; ++r) {
    vreg[r] = *(const f32x4*)(V + (size_t)(row0 + srow + r * 16) * ND + c4);
    wreg[r] = *(const f32x4*)(W + (size_t)(col0 + srow + r * 16) * ND + c4);
  }
  for (int k0 = 0; k0 < ND; k0 += 64) {
    __syncthreads();
#pragma unroll
    for (int r = 0; r < 8; ++r) {
      int row = srow + r * 16;
      u16x4 h, l;
#pragma unroll
      for (int j = 0; j < 4; ++j) {
        unsigned p = split2(vreg[r][j]);
        h[j] = (unsigned short)(p & 0xffffu); l[j] = (unsigned short)(p >> 16);
      }
      *(u16x4*)&Ah[row][c4] = h; *(u16x4*)&Al[row][c4] = l;
#pragma unroll
      for (int j = 0; j < 4; ++j) {
        unsigned p = split2(wreg[r][j]);
        h[j] = (unsigned short)(p & 0xffffu); l[j] = (unsigned short)(p >> 16);
      }
      *(u16x4*)&Bh[row][c4] = h; *(u16x4*)&Bl[row][c4] = l;
    }
    __syncthreads();
    if (k0 + 64 < ND) {
#pragma unroll
      for (int r = 0; r < 8; ++r) {
        vreg[r] = *(const f32x4*)(V + (size_t)(row0 + srow + r * 16) * ND + k0 + 64 + c4);
        wreg[r] = *(const f32x4*)(W + (size_t)(col0 + srow + r * 16) * ND + k0 + 64 + c4);
      }
    }
#pragma unroll
    for (int kk = 0; kk < 2; ++kk) {
      int kof = kk * 32 + ((lane >> 4) << 3);
      bf16x8 ah[4], al[4], bh[4], bl[4];
#pragma unroll
      for (int i = 0; i < 4; ++i) {
        int ra = wr + i * 16 + (lane & 15);
        ah[i] = *(const bf16x8*)&Ah[ra][kof];
        al[i] = *(const bf16x8*)&Al[ra][kof];
        int rb = wc + i * 16 + (lane & 15);
        bh[i] = *(const bf16x8*)&Bh[rb][kof];
        bl[i] = *(const bf16x8*)&Bl[rb][kof];
      }
#pragma unroll
      for (int i = 0; i < 4; ++i)
#pragma unroll
        for (int j = 0; j < 4; ++j) {
          acc[i][j] = mfma16(ah[i], bh[j], acc[i][j]);
          acc[i][j] = mfma16(ah[i], bl[j], acc[i][j]);
          acc[i][j] = mfma16(al[i], bh[j], acc[i][j]);
        }
    }
  }
  // epilogue: stage packed C-tile in LDS, coalesced 512B-run writes
  __syncthreads();
  unsigned* CT = (unsigned*)SMEM;                    // 128 x 134 u32
#pragma unroll
  for (int j = 0; j < 4; ++j) {
    int col_l = wc + j * 16 + (lane & 15);
    float bj = bias[col0 + col_l];
#pragma unroll
    for (int i = 0; i < 4; ++i) {
      int rb_l = wr + i * 16 + ((lane >> 4) << 2);
#pragma unroll
      for (int r = 0; r < 4; ++r) CT[(rb_l + r) * 134 + col_l] = split2(acc[i][j][r] + bj);
    }
  }
  __syncthreads();
#pragma unroll
  for (int it = 0; it < 32; ++it) {
    int idx = it * 256 + t;
    int row = idx >> 6, c2 = idx & 63;
    *(u32x2*)(kbuf + (size_t)(row0 + row) * 1024 + col0 + c2 * 2) =
        *(const u32x2*)&CT[row * 134 + c2 * 2];
  }
}

// ------- kernel 2: scores GEMM + fused block-softmax: writes e=exp(s-m_blk) bf16 + partials -------
__global__ __launch_bounds__(256, 2) void k_scores(const float* __restrict__ Q,
                                                   const unsigned int* __restrict__ kbuf,
                                                   unsigned short* __restrict__ ebase,
                                                   float2* __restrict__ partials) {
  int bid = blockIdx.x;
  int swz = (bid & 7) * 256 + (bid >> 3);
  int b = swz >> 6, rr2 = swz & 63, vt = rr2 >> 3, qt = rr2 & 7;
  int t = threadIdx.x, lane = t & 63, w = t >> 6, g = lane >> 4, l15 = lane & 15;
  int wr = (w >> 1) * 64, wc = (w & 1) * 64;
  __shared__ __align__(16) unsigned char SMEM[73728];
  auto Ah = (unsigned short(*)[72])(SMEM);
  auto Al = (unsigned short(*)[72])(SMEM + 18432);
  auto Bh = (unsigned short(*)[72])(SMEM + 36864);
  auto Bl = (unsigned short(*)[72])(SMEM + 55296);
  f32x4 acc[4][4] = {};
  const size_t qrow = (size_t)(b * NTQ + qt * 128);
  const size_t krow = (size_t)(b * NTV + vt * 128);
  int srow = t >> 4, c4 = (t & 15) * 4;

  f32x4 qreg[8]; u32x4 kreg[8];
#pragma unroll
  for (int r = 0; r < 8; ++r) {
    qreg[r] = *(const f32x4*)(Q + (qrow + srow + r * 16) * ND + c4);
    kreg[r] = *(const u32x4*)(kbuf + (krow + srow + r * 16) * 1024 + c4);
  }
  for (int k0 = 0; k0 < ND; k0 += 64) {
    __syncthreads();
#pragma unroll
    for (int r = 0; r < 8; ++r) {
      int row = srow + r * 16;
      u16x4 h, l;
#pragma unroll
      for (int j = 0; j < 4; ++j) {
        unsigned p = split2(qreg[r][j]);
        h[j] = (unsigned short)(p & 0xffffu); l[j] = (unsigned short)(p >> 16);
      }
      *(u16x4*)&Ah[row][c4] = h; *(u16x4*)&Al[row][c4] = l;
#pragma unroll
      for (int j = 0; j < 4; ++j) {
        h[j] = (unsigned short)(kreg[r][j] & 0xffffu);
        l[j] = (unsigned short)(kreg[r][j] >> 16);
      }
      *(u16x4*)&Bh[row][c4] = h; *(u16x4*)&Bl[row][c4] = l;
    }
    __syncthreads();
    if (k0 + 64 < ND) {
#pragma unroll
      for (int r = 0; r < 8; ++r) {
        qreg[r] = *(const f32x4*)(Q + (qrow + srow + r * 16) * ND + k0 + 64 + c4);
        kreg[r] = *(const u32x4*)(kbuf + (krow + srow + r * 16) * 1024 + k0 + 64 + c4);
      }
    }
#pragma unroll
    for (int kk = 0; kk < 2; ++kk) {
      int kof = kk * 32 + ((lane >> 4) << 3);
      bf16x8 ah[4], al[4], bh[4], bl[4];
#pragma unroll
      for (int i = 0; i < 4; ++i) {
        int ra = wr + i * 16 + (lane & 15);
        ah[i] = *(const bf16x8*)&Ah[ra][kof];
        al[i] = *(const bf16x8*)&Al[ra][kof];
        int rb = wc + i * 16 + (lane & 15);
        bh[i] = *(const bf16x8*)&Bh[rb][kof];
        bl[i] = *(const bf16x8*)&Bl[rb][kof];
      }
#pragma unroll
      for (int i = 0; i < 4; ++i)
#pragma unroll
        for (int j = 0; j < 4; ++j) {
          acc[i][j] = mfma16(ah[i], bh[j], acc[i][j]);
          acc[i][j] = mfma16(ah[i], bl[j], acc[i][j]);
          acc[i][j] = mfma16(al[i], bh[j], acc[i][j]);
        }
    }
  }
  // ---- fused block softmax: m over this block's 128 v per q; e tile bf16; partial (m,l) ----
  __syncthreads();
  auto E = (unsigned short(*)[136])(SMEM);      // 128 x 136 u16 = 34816 B (aliases Ah/Al)
  float* Lm = (float*)(SMEM + 36864);           // [128][2] f32 (aliases Bh)
  float* Ls = (float*)(SMEM + 37888);           // [128][2] f32
  // phase 1: per-wave max over its 64 v's
#pragma unroll
  for (int i = 0; i < 4; ++i)
#pragma unroll
    for (int r = 0; r < 4; ++r) {
      float m = fmaxf(fmaxf(acc[i][0][r], acc[i][1][r]), fmaxf(acc[i][2][r], acc[i][3][r]));
#pragma unroll
      for (int msk = 1; msk < 16; msk <<= 1) m = fmaxf(m, __shfl_xor(m, msk));
      if (l15 == 0) Lm[(wr + i * 16 + g * 4 + r) * 2 + (w & 1)] = m;
    }
  __syncthreads();
  // phase 2: e = exp(s - m_f); row sums; e -> E (bf16)
#pragma unroll
  for (int i = 0; i < 4; ++i)
#pragma unroll
    for (int r = 0; r < 4; ++r) {
      int ql = wr + i * 16 + g * 4 + r;
      float mf = fmaxf(Lm[ql * 2], Lm[ql * 2 + 1]);
      float s = 0.f;
#pragma unroll
      for (int j = 0; j < 4; ++j) {
        float e = __expf(acc[i][j][r] - mf);
        s += e;
        E[wc + j * 16 + l15][ql] = f2bf(e);
      }
#pragma unroll
      for (int msk = 1; msk < 16; msk <<= 1) s += __shfl_xor(s, msk);
      if (l15 == 0) Ls[ql * 2 + (w & 1)] = s;
    }
  __syncthreads();
  if (t < 128) {
    float mf = fmaxf(Lm[t * 2], Lm[t * 2 + 1]);
    float lf = Ls[t * 2] + Ls[t * 2 + 1];
    partials[(((size_t)(b * 8 + vt)) << 10) + qt * 128 + t] = make_float2(mf, lf);
  }
  // E -> global e-buffer (row (b,v) = second half of out1 row; 256B runs)
#pragma unroll
  for (int it = 0; it < 8; ++it) {
    int idx = it * 256 + t;
    int row = idx >> 4, ch = idx & 15;
    *(u16x8*)(ebase + (size_t)(b * 1024 + vt * 128 + row) * 2048 + 1024 + qt * 128 + ch * 8) =
        *(const u16x8*)&E[row][ch * 8];
  }
}

// ------- kernel 3: combine 8 partials per (b,q) -> global (M, 1/L) -------
__global__ __launch_bounds__(256) void k_combine(const float2* __restrict__ partials,
                                                 float2* __restrict__ stats) {
  int idx = blockIdx.x * 256 + threadIdx.x;   // 32768
  int b = idx >> 10, q = idx & 1023;
  float2 p[8];
  float M = -3.0e38f;
#pragma unroll
  for (int vt = 0; vt < 8; ++vt) {
    p[vt] = partials[(((size_t)(b * 8 + vt)) << 10) + q];
    M = fmaxf(M, p[vt].x);
  }
  float L = 0.f;
#pragma unroll
  for (int vt = 0; vt < 8; ++vt) L += p[vt].y * __expf(p[vt].x - M);
  stats[idx] = make_float2(M, 1.0f / L);
}

// ------- kernel 4: alpha = e * scale (write out2), context = alpha @ V (V from L2) -------
__global__ __launch_bounds__(512, 4) void k_pv(const unsigned short* __restrict__ ebase,
                                               const unsigned short* __restrict__ Vt,
                                               const float2* __restrict__ stats,
                                               const float2* __restrict__ partials,
                                               float* __restrict__ out2,
                                               float* __restrict__ out1) {
  int bid = blockIdx.x;
  int swz = (bid & 7) * 64 + (bid >> 3);
  int b = swz >> 4, qt = swz & 15;
  int t = threadIdx.x, lane = t & 63, w = t >> 6;
  int wq = (w >> 2) * 32, wd = (w & 3) * 128;
  int q0 = qt * 64;
  __shared__ __align__(16) unsigned char SMEM[66560];
  auto Elds = (unsigned short(*)[72])(SMEM);          // 64x72 u16
  auto Asm  = (unsigned short(*)[72])(SMEM + 9216);   // 64x72 u16
  auto SF   = (float(*)[68])(SMEM + 18432);           // 64x68 f32
  float* CT = (float*)SMEM;                           // epilogue alias (64x260 f32)

  f32x4 acc[2][8] = {};
  float Mq[4], iLq[4];
  int vb = t & 15, qb = t >> 4;    // t<256 roles
  if (t < 256) {
#pragma unroll
    for (int j = 0; j < 4; ++j) {
      float2 st = stats[b * NTQ + q0 + qb * 4 + j];
      Mq[j] = st.x; iLq[j] = st.y;
    }
  }
  int erow = t >> 3, ec8 = (t & 7) * 8;
  u16x8 ereg = *(const u16x8*)(ebase + (size_t)(b * 1024 + erow) * 2048 + 1024 + q0 + ec8);

  for (int v0 = 0; v0 < NTV; v0 += 64) {
    __syncthreads();
    *(u16x8*)&Elds[erow][ec8] = ereg;
    __syncthreads();
    if (t < 256) {
      float sc[4];
#pragma unroll
      for (int j = 0; j < 4; ++j) {
        float2 p = partials[(((size_t)(b * 8 + (v0 >> 7))) << 10) + q0 + qb * 4 + j];
        sc[j] = __expf(p.x - Mq[j]) * iLq[j];
      }
      f32x4 al_[4];
#pragma unroll
      for (int i = 0; i < 4; ++i) {
        u16x4 ev = *(const u16x4*)&Elds[vb * 4 + i][qb * 4];
        f32x4 a;
#pragma unroll
        for (int j = 0; j < 4; ++j) a[j] = bf2f(ev[j]) * sc[j];
        *(f32x4*)&SF[vb * 4 + i][qb * 4] = a;
        al_[i] = a;
      }
#pragma unroll
      for (int j = 0; j < 4; ++j) {
        u16x4 col;
#pragma unroll
        for (int i = 0; i < 4; ++i) col[i] = f2bf(al_[i][j]);
        *(u16x4*)&Asm[qb * 4 + j][vb * 4] = col;
      }
    }
    if (v0 + 64 < NTV)
      ereg = *(const u16x8*)(ebase + (size_t)(b * 1024 + v0 + 64 + erow) * 2048 + 1024 + q0 + ec8);
    __syncthreads();
    // alpha write (256B runs), overlapped with MFMA
#pragma unroll
    for (int ps = 0; ps < 2; ++ps) {
      int idx = ps * 512 + t;
      int row = idx >> 4, ch = idx & 15;
      *(f32x4*)(out2 + (size_t)b * NTV * NTQ + (size_t)(v0 + row) * NTQ + q0 + ch * 4) =
          *(const f32x4*)&SF[row][ch * 4];
    }
    // MFMA: A from Asm (LDS), B straight from Vt (L2-resident)
#pragma unroll
    for (int kk = 0; kk < 2; ++kk) {
      int kof = kk * 32 + ((lane >> 4) << 3);
      bf16x8 af[2], bfr[8];
#pragma unroll
      for (int i = 0; i < 2; ++i)
        af[i] = *(const bf16x8*)&Asm[wq + i * 16 + (lane & 15)][kof];
#pragma unroll
      for (int j = 0; j < 8; ++j)
        bfr[j] = *(const bf16x8*)(Vt + (size_t)(b * ND + wd + j * 16 + (lane & 15)) * NTV + v0 + kof);
#pragma unroll
      for (int i = 0; i < 2; ++i)
#pragma unroll
        for (int j = 0; j < 8; ++j) acc[i][j] = mfma16(af[i], bfr[j], acc[i][j]);
    }
  }
  // epilogue: context via LDS staging, 512B runs
#pragma unroll
  for (int h = 0; h < 2; ++h) {
    __syncthreads();
    if (((w & 3) >> 1) == h) {
      int dbase = wd - h * 256;
#pragma unroll
      for (int i = 0; i < 2; ++i)
#pragma unroll
        for (int j = 0; j < 8; ++j) {
          int q_l = wq + i * 16 + ((lane >> 4) << 2);
          int d_l = dbase + j * 16 + (lane & 15);
#pragma unroll
          for (int r = 0; r < 4; ++r) CT[(q_l + r) * 260 + d_l] = acc[i][j][r];
        }
    }
    __syncthreads();
#pragma unroll
    for (int it = 0; it < 16; ++it) {
      int idx = it * 512 + t;
      int row = idx >> 7, c2 = idx & 127;
      *(f32x2*)(out1 + (size_t)(b * NTQ + q0 + row) * 1024 + h * 256 + c2 * 2) =
          *(const f32x2*)&CT[row * 260 + c2 * 2];
    }
  }
}

// ------- kernel 5: concat query into out1 second halves (after k_pv consumed e) -------
__global__ __launch_bounds__(256) void k_qcat(const float* __restrict__ Q,
                                              float* __restrict__ out1) {
  int base = blockIdx.x * 1024 + threadIdx.x;
#pragma unroll
  for (int k = 0; k < 4; ++k) {
    int idx = base + k * 256;                  // 0 .. 4194303
    int row = idx >> 7, quad = idx & 127;
    *(f32x4*)(out1 + (size_t)row * 1024 + 512 + quad * 4) =
        *(const f32x4*)(Q + (size_t)row * 512 + quad * 4);
  }
}

extern "C" void kernel_launch(void* const* d_in, const int* in_sizes, int n_in,
                              void* d_out, int out_size, void* d_ws, size_t ws_size,
                              hipStream_t stream) {
  const float* Q    = (const float*)d_in[0];
  const float* V    = (const float*)d_in[1];
  const float* W    = (const float*)d_in[2];
  const float* bias = (const float*)d_in[3];

  float* out1 = (float*)d_out;                                   // context_cat [B,TQ,2D]
  float* out2 = (float*)d_out + (size_t)NB * NTQ * (2 * ND);     // alignment_t [B,TV,TQ]

  unsigned short* Vt = (unsigned short*)d_ws;                    // bf16 [B,D,TV]  32MB
  float2* stats    = (float2*)((char*)d_ws + 33554432);          // 256KB
  float2* partials = (float2*)((char*)d_ws + 33554432 + 262144); // 2MB

  unsigned int* kbuf = (unsigned int*)out1;          // keys hi|lo packed: out1 row first-halves
  unsigned short* ebase = (unsigned short*)out1;     // e bf16: out1 row second-halves

  k_vt<<<dim3(16, 8, 32), 256, 0, stream>>>(V, Vt);
  k_keys<<<1024, 256, 0, stream>>>(V, W, bias, kbuf);
  k_scores<<<2048, 256, 0, stream>>>(Q, kbuf, ebase, partials);
  k_combine<<<128, 256, 0, stream>>>(partials, stats);
  k_pv<<<512, 512, 0, stream>>>(ebase, Vt, stats, partials, out2, out1);
  k_qcat<<<4096, 256, 0, stream>>>(Q, out1);
}

// Round 5
// 459.696 us; speedup vs baseline: 1.1217x; 1.1217x over previous
//
#include <hip/hip_runtime.h>
#include <hip/hip_bf16.h>

#define NB  32
#define NTQ 1024
#define NTV 1024
#define ND  512

typedef float f32x4 __attribute__((ext_vector_type(4)));
typedef float f32x2 __attribute__((ext_vector_type(2)));
typedef __bf16 bf16x8 __attribute__((ext_vector_type(8)));
typedef unsigned short u16x4 __attribute__((ext_vector_type(4)));
typedef unsigned short u16x8 __attribute__((ext_vector_type(8)));
typedef unsigned int u32x2 __attribute__((ext_vector_type(2)));
typedef unsigned int u32x4 __attribute__((ext_vector_type(4)));

static __device__ __forceinline__ unsigned short f2bf(float f) {   // RTN-even
  unsigned u = __builtin_bit_cast(unsigned, f);
  u += 0x7fffu + ((u >> 16) & 1u);
  return (unsigned short)(u >> 16);
}
static __device__ __forceinline__ float bf2f(unsigned short h) {
  unsigned u = ((unsigned)h) << 16;
  return __builtin_bit_cast(float, u);
}
// trunc split: packed (hi | lo<<16)
static __device__ __forceinline__ unsigned split2(float x) {
  unsigned u = __builtin_bit_cast(unsigned, x);
  unsigned h = u >> 16;
  float hf = __builtin_bit_cast(float, u & 0xffff0000u);
  unsigned l = __builtin_bit_cast(unsigned, x - hf) >> 16;
  return h | (l << 16);
}
static __device__ __forceinline__ f32x4 mfma16(bf16x8 a, bf16x8 b, f32x4 c) {
  return __builtin_amdgcn_mfma_f32_16x16x32_bf16(a, b, c, 0, 0, 0);
}

// ---------------- kernel 0: V [B,TV,D] f32 -> Vt [B,D,TV] bf16 ----------------
__global__ __launch_bounds__(256) void k_vt(const float* __restrict__ V,
                                            unsigned short* __restrict__ Vt) {
  int vt = blockIdx.x, dt = blockIdx.y, b = blockIdx.z;
  int t = threadIdx.x;
  __shared__ unsigned short L[64][72];
#pragma unroll
  for (int r = 0; r < 4; ++r) {
    int v = (t >> 4) + r * 16;
    int c4 = (t & 15) * 4;
    f32x4 x = *(const f32x4*)(V + (size_t)(b * NTV + vt * 64 + v) * ND + dt * 64 + c4);
    u16x4 h;
#pragma unroll
    for (int j = 0; j < 4; ++j) h[j] = f2bf(x[j]);
    *(u16x4*)&L[v][c4] = h;
  }
  __syncthreads();
#pragma unroll
  for (int r = 0; r < 4; ++r) {
    int d = (t >> 4) + r * 16;
    int v4 = (t & 15) * 4;
    u16x4 o;
#pragma unroll
    for (int i = 0; i < 4; ++i) o[i] = L[v4 + i][d];
    *(u16x4*)(Vt + (size_t)(b * ND + dt * 64 + d) * NTV + vt * 64 + v4) = o;
  }
}

// ------- kernel 1: keys = V @ W^T + bias, trunc-split, reg-prefetch pipeline -------
__global__ __launch_bounds__(256, 2) void k_keys(const float* __restrict__ V,
                                                 const float* __restrict__ W,
                                                 const float* __restrict__ bias,
                                                 unsigned int* __restrict__ kbuf) {
  int bid = blockIdx.x;
  int swz = (bid & 7) * 128 + (bid >> 3);
  int bm = swz >> 2, bn = swz & 3;
  int t = threadIdx.x, lane = t & 63, w = t >> 6;
  int wr = (w >> 1) * 64, wc = (w & 1) * 64;
  __shared__ __align__(16) unsigned char SMEM[73728];
  auto Ah = (unsigned short(*)[72])(SMEM);
  auto Al = (unsigned short(*)[72])(SMEM + 18432);
  auto Bh = (unsigned short(*)[72])(SMEM + 36864);
  auto Bl = (unsigned short(*)[72])(SMEM + 55296);
  f32x4 acc[4][4] = {};
  const int row0 = bm * 128, col0 = bn * 128;
  int srow = t >> 4, c4 = (t & 15) * 4;

  f32x4 vreg[8], wreg[8];
#pragma unroll
  for (int r = 0; r < 8; ++r) {
    vreg[r] = *(const f32x4*)(V + (size_t)(row0 + srow + r * 16) * ND + c4);
    wreg[r] = *(const f32x4*)(W + (size_t)(col0 + srow + r * 16) * ND + c4);
  }
  for (int k0 = 0; k0 < ND; k0 += 64) {
    __syncthreads();
#pragma unroll
    for (int r = 0; r < 8; ++r) {
      int row = srow + r * 16;
      u16x4 h, l;
#pragma unroll
      for (int j = 0; j < 4; ++j) {
        unsigned p = split2(vreg[r][j]);
        h[j] = (unsigned short)(p & 0xffffu); l[j] = (unsigned short)(p >> 16);
      }
      *(u16x4*)&Ah[row][c4] = h; *(u16x4*)&Al[row][c4] = l;
#pragma unroll
      for (int j = 0; j < 4; ++j) {
        unsigned p = split2(wreg[r][j]);
        h[j] = (unsigned short)(p & 0xffffu); l[j] = (unsigned short)(p >> 16);
      }
      *(u16x4*)&Bh[row][c4] = h; *(u16x4*)&Bl[row][c4] = l;
    }
    __syncthreads();
    if (k0 + 64 < ND) {
#pragma unroll
      for (int r = 0; r < 8; ++r) {
        vreg[r] = *(const f32x4*)(V + (size_t)(row0 + srow + r * 16) * ND + k0 + 64 + c4);
        wreg[r] = *(const f32x4*)(W + (size_t)(col0 + srow + r * 16) * ND + k0 + 64 + c4);
      }
    }
#pragma unroll
    for (int kk = 0; kk < 2; ++kk) {
      int kof = kk * 32 + ((lane >> 4) << 3);
      bf16x8 ah[4], al[4], bh[4], bl[4];
#pragma unroll
      for (int i = 0; i < 4; ++i) {
        int ra = wr + i * 16 + (lane & 15);
        ah[i] = *(const bf16x8*)&Ah[ra][kof];
        al[i] = *(const bf16x8*)&Al[ra][kof];
        int rb = wc + i * 16 + (lane & 15);
        bh[i] = *(const bf16x8*)&Bh[rb][kof];
        bl[i] = *(const bf16x8*)&Bl[rb][kof];
      }
#pragma unroll
      for (int i = 0; i < 4; ++i)
#pragma unroll
        for (int j = 0; j < 4; ++j) {
          acc[i][j] = mfma16(ah[i], bh[j], acc[i][j]);
          acc[i][j] = mfma16(ah[i], bl[j], acc[i][j]);
          acc[i][j] = mfma16(al[i], bh[j], acc[i][j]);
        }
    }
  }
  // epilogue: stage packed C-tile in LDS, coalesced writes
  __syncthreads();
  unsigned* CT = (unsigned*)SMEM;                    // 128 x 134 u32
#pragma unroll
  for (int j = 0; j < 4; ++j) {
    int col_l = wc + j * 16 + (lane & 15);
    float bj = bias[col0 + col_l];
#pragma unroll
    for (int i = 0; i < 4; ++i) {
      int rb_l = wr + i * 16 + ((lane >> 4) << 2);
#pragma unroll
      for (int r = 0; r < 4; ++r) CT[(rb_l + r) * 134 + col_l] = split2(acc[i][j][r] + bj);
    }
  }
  __syncthreads();
#pragma unroll
  for (int it = 0; it < 32; ++it) {
    int idx = it * 256 + t;
    int row = idx >> 6, c2 = idx & 63;
    *(u32x2*)(kbuf + (size_t)(row0 + row) * 1024 + col0 + c2 * 2) =
        *(const u32x2*)&CT[row * 134 + c2 * 2];
  }
}

// ------- kernel 2: scores GEMM + fused block-softmax: writes e=exp(s-m_blk) bf16 + partials -------
__global__ __launch_bounds__(256, 2) void k_scores(const float* __restrict__ Q,
                                                   const unsigned int* __restrict__ kbuf,
                                                   unsigned short* __restrict__ ebase,
                                                   float2* __restrict__ partials) {
  int bid = blockIdx.x;
  int swz = (bid & 7) * 256 + (bid >> 3);
  int b = swz >> 6, rr2 = swz & 63, vt = rr2 >> 3, qt = rr2 & 7;
  int t = threadIdx.x, lane = t & 63, w = t >> 6, g = lane >> 4, l15 = lane & 15;
  int wr = (w >> 1) * 64, wc = (w & 1) * 64;
  __shared__ __align__(16) unsigned char SMEM[73728];
  auto Ah = (unsigned short(*)[72])(SMEM);
  auto Al = (unsigned short(*)[72])(SMEM + 18432);
  auto Bh = (unsigned short(*)[72])(SMEM + 36864);
  auto Bl = (unsigned short(*)[72])(SMEM + 55296);
  f32x4 acc[4][4] = {};
  const size_t qrow = (size_t)(b * NTQ + qt * 128);
  const size_t krow = (size_t)(b * NTV + vt * 128);
  int srow = t >> 4, c4 = (t & 15) * 4;

  f32x4 qreg[8]; u32x4 kreg[8];
#pragma unroll
  for (int r = 0; r < 8; ++r) {
    qreg[r] = *(const f32x4*)(Q + (qrow + srow + r * 16) * ND + c4);
    kreg[r] = *(const u32x4*)(kbuf + (krow + srow + r * 16) * 1024 + c4);
  }
  for (int k0 = 0; k0 < ND; k0 += 64) {
    __syncthreads();
#pragma unroll
    for (int r = 0; r < 8; ++r) {
      int row = srow + r * 16;
      u16x4 h, l;
#pragma unroll
      for (int j = 0; j < 4; ++j) {
        unsigned p = split2(qreg[r][j]);
        h[j] = (unsigned short)(p & 0xffffu); l[j] = (unsigned short)(p >> 16);
      }
      *(u16x4*)&Ah[row][c4] = h; *(u16x4*)&Al[row][c4] = l;
#pragma unroll
      for (int j = 0; j < 4; ++j) {
        h[j] = (unsigned short)(kreg[r][j] & 0xffffu);
        l[j] = (unsigned short)(kreg[r][j] >> 16);
      }
      *(u16x4*)&Bh[row][c4] = h; *(u16x4*)&Bl[row][c4] = l;
    }
    __syncthreads();
    if (k0 + 64 < ND) {
#pragma unroll
      for (int r = 0; r < 8; ++r) {
        qreg[r] = *(const f32x4*)(Q + (qrow + srow + r * 16) * ND + k0 + 64 + c4);
        kreg[r] = *(const u32x4*)(kbuf + (krow + srow + r * 16) * 1024 + k0 + 64 + c4);
      }
    }
#pragma unroll
    for (int kk = 0; kk < 2; ++kk) {
      int kof = kk * 32 + ((lane >> 4) << 3);
      bf16x8 ah[4], al[4], bh[4], bl[4];
#pragma unroll
      for (int i = 0; i < 4; ++i) {
        int ra = wr + i * 16 + (lane & 15);
        ah[i] = *(const bf16x8*)&Ah[ra][kof];
        al[i] = *(const bf16x8*)&Al[ra][kof];
        int rb = wc + i * 16 + (lane & 15);
        bh[i] = *(const bf16x8*)&Bh[rb][kof];
        bl[i] = *(const bf16x8*)&Bl[rb][kof];
      }
#pragma unroll
      for (int i = 0; i < 4; ++i)
#pragma unroll
        for (int j = 0; j < 4; ++j) {
          acc[i][j] = mfma16(ah[i], bh[j], acc[i][j]);
          acc[i][j] = mfma16(ah[i], bl[j], acc[i][j]);
          acc[i][j] = mfma16(al[i], bh[j], acc[i][j]);
        }
    }
  }
  // ---- fused block softmax: m over this block's 128 v per q; e tile bf16; partial (m,l) ----
  __syncthreads();
  auto E = (unsigned short(*)[136])(SMEM);      // 128 x 136 u16 (aliases Ah/Al)
  float* Lm = (float*)(SMEM + 36864);           // [128][2] f32 (aliases Bh)
  float* Ls = (float*)(SMEM + 37888);
#pragma unroll
  for (int i = 0; i < 4; ++i)
#pragma unroll
    for (int r = 0; r < 4; ++r) {
      float m = fmaxf(fmaxf(acc[i][0][r], acc[i][1][r]), fmaxf(acc[i][2][r], acc[i][3][r]));
#pragma unroll
      for (int msk = 1; msk < 16; msk <<= 1) m = fmaxf(m, __shfl_xor(m, msk));
      if (l15 == 0) Lm[(wr + i * 16 + g * 4 + r) * 2 + (w & 1)] = m;
    }
  __syncthreads();
#pragma unroll
  for (int i = 0; i < 4; ++i)
#pragma unroll
    for (int r = 0; r < 4; ++r) {
      int ql = wr + i * 16 + g * 4 + r;
      float mf = fmaxf(Lm[ql * 2], Lm[ql * 2 + 1]);
      float s = 0.f;
#pragma unroll
      for (int j = 0; j < 4; ++j) {
        float e = __expf(acc[i][j][r] - mf);
        s += e;
        E[wc + j * 16 + l15][ql] = f2bf(e);
      }
#pragma unroll
      for (int msk = 1; msk < 16; msk <<= 1) s += __shfl_xor(s, msk);
      if (l15 == 0) Ls[ql * 2 + (w & 1)] = s;
    }
  __syncthreads();
  if (t < 128) {
    float mf = fmaxf(Lm[t * 2], Lm[t * 2 + 1]);
    float lf = Ls[t * 2] + Ls[t * 2 + 1];
    partials[(((size_t)(b * 8 + vt)) << 10) + qt * 128 + t] = make_float2(mf, lf);
  }
#pragma unroll
  for (int it = 0; it < 8; ++it) {
    int idx = it * 256 + t;
    int row = idx >> 4, ch = idx & 15;
    *(u16x8*)(ebase + (size_t)(b * 1024 + vt * 128 + row) * 2048 + 1024 + qt * 128 + ch * 8) =
        *(const u16x8*)&E[row][ch * 8];
  }
}

// ------- kernel 3: combine 8 partials per (b,q) -> global (M, 1/L) -------
__global__ __launch_bounds__(256) void k_combine(const float2* __restrict__ partials,
                                                 float2* __restrict__ stats) {
  int idx = blockIdx.x * 256 + threadIdx.x;   // 32768
  int b = idx >> 10, q = idx & 1023;
  float2 p[8];
  float M = -3.0e38f;
#pragma unroll
  for (int vt = 0; vt < 8; ++vt) {
    p[vt] = partials[(((size_t)(b * 8 + vt)) << 10) + q];
    M = fmaxf(M, p[vt].x);
  }
  float L = 0.f;
#pragma unroll
  for (int vt = 0; vt < 8; ++vt) L += p[vt].y * __expf(p[vt].x - M);
  stats[idx] = make_float2(M, 1.0f / L);
}

// ------- kernel 4: context = alpha @ V ; pure GEMM, 64q x 256d per block -------
// e loaded coalesced + reg-prefetched; transpose+scale into XOR-swizzled Asm; Vt staged in LDS.
__global__ __launch_bounds__(256, 3) void k_pv(const unsigned short* __restrict__ ebase,
                                               const unsigned short* __restrict__ Vt,
                                               const float2* __restrict__ stats,
                                               const float2* __restrict__ partials,
                                               float* __restrict__ out1) {
  int bid = blockIdx.x;
  int swz = (bid & 7) * 128 + (bid >> 3);        // 1024 blocks
  int b = swz >> 5, qt = (swz >> 1) & 15, dt = swz & 1;
  int t = threadIdx.x, lane = t & 63, w = t >> 6;   // w = d-wave 0..3
  int l15 = lane & 15, g = lane >> 4;
  int q0 = qt * 64, d0 = dt * 256;
  __shared__ __align__(16) unsigned char SMEM[46080];
  auto Asm = (unsigned short(*)[72])(SMEM);          // [64 q][72] (XOR-swizzled cols)
  auto Bsm = (unsigned short(*)[72])(SMEM + 9216);   // [256 d][72]
  f32x4 acc[4][4] = {};
  int qb = t & 15, vb = t >> 4;   // thread owns q = qb*4..+3, v = vb*4..+3 (per tile)
  float M4[4], iL4[4];
#pragma unroll
  for (int j = 0; j < 4; ++j) {
    float2 st = stats[b * NTQ + q0 + qb * 4 + j];
    M4[j] = st.x; iL4[j] = st.y;
  }
  const size_t ebrow = (size_t)b * 1024;
  u16x4 ereg[4];
#pragma unroll
  for (int i = 0; i < 4; ++i)
    ereg[i] = *(const u16x4*)(ebase + (ebrow + vb * 4 + i) * 2048 + 1024 + q0 + qb * 4);

  float sc[4];
  for (int v0 = 0; v0 < NTV; v0 += 64) {
    if ((v0 & 127) == 0) {   // new 128-v scores block -> refresh scale
      int vt128 = v0 >> 7;
#pragma unroll
      for (int j = 0; j < 4; ++j) {
        float2 p = partials[(((size_t)(b * 8 + vt128)) << 10) + q0 + qb * 4 + j];
        sc[j] = __expf(p.x - M4[j]) * iL4[j];
      }
    }
    __syncthreads();   // prev MFMA done, LDS reusable
    // transpose + scale e -> Asm (XOR-swizzled store)
    {
      u16x4 col[4];
#pragma unroll
      for (int j = 0; j < 4; ++j)
#pragma unroll
        for (int i = 0; i < 4; ++i) col[j][i] = f2bf(bf2f(ereg[i][j]) * sc[j]);
#pragma unroll
      for (int j = 0; j < 4; ++j) {
        int q = qb * 4 + j;
        int cs = (vb * 4) ^ (((q >> 2) & 7) << 3);
        *(u16x4*)&Asm[q][cs] = col[j];
      }
    }
    // stage Vt tile [256 d][64 v]
#pragma unroll
    for (int k = 0; k < 8; ++k) {
      int id = k * 256 + t;
      int row = id >> 3, c8 = (id & 7) * 8;
      *(u16x8*)&Bsm[row][c8] =
          *(const u16x8*)(Vt + ((size_t)b * ND + d0 + row) * NTV + v0 + c8);
    }
    // prefetch next e tile (lands under MFMA)
    if (v0 + 64 < NTV) {
#pragma unroll
      for (int i = 0; i < 4; ++i)
        ereg[i] = *(const u16x4*)(ebase + (ebrow + v0 + 64 + vb * 4 + i) * 2048 + 1024 + q0 + qb * 4);
    }
    __syncthreads();
#pragma unroll
    for (int kk = 0; kk < 2; ++kk) {
      int kof = kk * 32 + g * 8;
      bf16x8 af[4], bfr[4];
#pragma unroll
      for (int i = 0; i < 4; ++i) {
        int row = i * 16 + l15;
        af[i] = *(const bf16x8*)&Asm[row][kof ^ (((row >> 2) & 7) << 3)];
      }
#pragma unroll
      for (int j = 0; j < 4; ++j) bfr[j] = *(const bf16x8*)&Bsm[w * 64 + j * 16 + l15][kof];
#pragma unroll
      for (int i = 0; i < 4; ++i)
#pragma unroll
        for (int j = 0; j < 4; ++j) acc[i][j] = mfma16(af[i], bfr[j], acc[i][j]);
    }
  }
  // epilogue: context tile via LDS, 512B runs, two 128-d halves
  float* CT = (float*)SMEM;   // [64][132] f32 = 33792 B
#pragma unroll
  for (int h = 0; h < 2; ++h) {
    __syncthreads();
    if ((w >> 1) == h) {
      int dl0 = (w & 1) * 64;
#pragma unroll
      for (int i = 0; i < 4; ++i)
#pragma unroll
        for (int j = 0; j < 4; ++j) {
          int ql = i * 16 + g * 4;
          int dl = dl0 + j * 16 + l15;
#pragma unroll
          for (int r = 0; r < 4; ++r) CT[(ql + r) * 132 + dl] = acc[i][j][r];
        }
    }
    __syncthreads();
#pragma unroll
    for (int it = 0; it < 8; ++it) {
      int idx = it * 256 + t;
      int row = idx >> 5, c4 = idx & 31;
      *(f32x4*)(out1 + (size_t)(b * NTQ + q0 + row) * 1024 + d0 + h * 128 + c4 * 4) =
          *(const f32x4*)&CT[row * 132 + c4 * 4];
    }
  }
}

// ------- kernel 5: alpha = e*sc -> out2 (coalesced rows) + fused Q-concat into out1 -------
// NOTE: ebase and out1 alias (same d_out region) -> no __restrict__ on them.
__global__ __launch_bounds__(256) void k_alpha(const unsigned short* ebase,
                                               const float* __restrict__ Q,
                                               const float2* __restrict__ stats,
                                               const float2* __restrict__ partials,
                                               float* __restrict__ out2,
                                               float* out1) {
  int bid = blockIdx.x;                       // 1024
  int swz = (bid & 7) * 128 + (bid >> 3);
  int b = swz >> 5, vt = (swz >> 2) & 7, quarter = swz & 3;
  int t = threadIdx.x;
  __shared__ float scq[1024];
#pragma unroll
  for (int k = 0; k < 4; ++k) {
    int q = k * 256 + t;
    float2 st = stats[b * NTQ + q];
    float2 p  = partials[(((size_t)(b * 8 + vt)) << 10) + q];
    scq[q] = __expf(p.x - st.x) * st.y;
  }
  __syncthreads();
  f32x4 s4 = *(const f32x4*)&scq[t * 4];
#pragma unroll 2
  for (int r = 0; r < 32; ++r) {
    int v = vt * 128 + quarter * 32 + r;
    size_t row = (size_t)(b * 1024 + v);
    // read e (bf16) for my 4 q's
    u16x4 ev = *(const u16x4*)(ebase + row * 2048 + 1024 + t * 4);
    f32x4 a;
#pragma unroll
    for (int j = 0; j < 4; ++j) a[j] = bf2f(ev[j]) * s4[j];
    *(f32x4*)(out2 + row * 1024 + t * 4) = a;              // alignment_t row (coalesced)
    // fused Q concat: overwrite the exact bytes this thread just read
    f32x2 qv = *(const f32x2*)(Q + row * 512 + t * 2);
    *(f32x2*)(out1 + row * 1024 + 512 + t * 2) = qv;
  }
}

extern "C" void kernel_launch(void* const* d_in, const int* in_sizes, int n_in,
                              void* d_out, int out_size, void* d_ws, size_t ws_size,
                              hipStream_t stream) {
  const float* Q    = (const float*)d_in[0];
  const float* V    = (const float*)d_in[1];
  const float* W    = (const float*)d_in[2];
  const float* bias = (const float*)d_in[3];

  float* out1 = (float*)d_out;                                   // context_cat [B,TQ,2D]
  float* out2 = (float*)d_out + (size_t)NB * NTQ * (2 * ND);     // alignment_t [B,TV,TQ]

  unsigned short* Vt = (unsigned short*)d_ws;                    // bf16 [B,D,TV]  32MB
  float2* stats    = (float2*)((char*)d_ws + 33554432);          // 256KB
  float2* partials = (float2*)((char*)d_ws + 33554432 + 262144); // 2MB

  unsigned int* kbuf = (unsigned int*)out1;          // keys hi|lo packed: out1 row first-halves
  unsigned short* ebase = (unsigned short*)out1;     // e bf16: out1 row second-halves

  k_vt<<<dim3(16, 8, 32), 256, 0, stream>>>(V, Vt);
  k_keys<<<1024, 256, 0, stream>>>(V, W, bias, kbuf);
  k_scores<<<2048, 256, 0, stream>>>(Q, kbuf, ebase, partials);
  k_combine<<<128, 256, 0, stream>>>(partials, stats);
  k_pv<<<1024, 256, 0, stream>>>(ebase, Vt, stats, partials, out1);
  k_alpha<<<1024, 256, 0, stream>>>(ebase, Q, stats, partials, out2, out1);
}

// Round 7
// 340.957 us; speedup vs baseline: 1.5124x; 1.3483x over previous
//
#include <hip/hip_runtime.h>
#include <hip/hip_bf16.h>

#define NB  32
#define NTQ 1024
#define NTV 1024
#define ND  512

typedef float f32x4 __attribute__((ext_vector_type(4)));
typedef float f32x2 __attribute__((ext_vector_type(2)));
typedef __bf16 bf16x8 __attribute__((ext_vector_type(8)));
typedef unsigned short u16x4 __attribute__((ext_vector_type(4)));
typedef unsigned short u16x8 __attribute__((ext_vector_type(8)));
typedef unsigned int u32x2 __attribute__((ext_vector_type(2)));
typedef unsigned int u32x4 __attribute__((ext_vector_type(4)));

static __device__ __forceinline__ unsigned short f2bf(float f) {   // RTN-even
  unsigned u = __builtin_bit_cast(unsigned, f);
  u += 0x7fffu + ((u >> 16) & 1u);
  return (unsigned short)(u >> 16);
}
static __device__ __forceinline__ float bf2f(unsigned short h) {
  unsigned u = ((unsigned)h) << 16;
  return __builtin_bit_cast(float, u);
}
// trunc split: packed (hi | lo<<16)
static __device__ __forceinline__ unsigned split2(float x) {
  unsigned u = __builtin_bit_cast(unsigned, x);
  unsigned h = u >> 16;
  float hf = __builtin_bit_cast(float, u & 0xffff0000u);
  unsigned l = __builtin_bit_cast(unsigned, x - hf) >> 16;
  return h | (l << 16);
}
static __device__ __forceinline__ f32x4 mfma16(bf16x8 a, bf16x8 b, f32x4 c) {
  return __builtin_amdgcn_mfma_f32_16x16x32_bf16(a, b, c, 0, 0, 0);
}

// ---------------- kernel 0: V [B,TV,D] f32 -> Vt [B,D,TV] bf16 ----------------
__global__ __launch_bounds__(256) void k_vt(const float* __restrict__ V,
                                            unsigned short* __restrict__ Vt) {
  int vt = blockIdx.x, dt = blockIdx.y, b = blockIdx.z;
  int t = threadIdx.x;
  __shared__ unsigned short L[64][72];
#pragma unroll
  for (int r = 0; r < 4; ++r) {
    int v = (t >> 4) + r * 16;
    int c4 = (t & 15) * 4;
    f32x4 x = *(const f32x4*)(V + (size_t)(b * NTV + vt * 64 + v) * ND + dt * 64 + c4);
    u16x4 h;
#pragma unroll
    for (int j = 0; j < 4; ++j) h[j] = f2bf(x[j]);
    *(u16x4*)&L[v][c4] = h;
  }
  __syncthreads();
#pragma unroll
  for (int r = 0; r < 4; ++r) {
    int d = (t >> 4) + r * 16;
    int v4 = (t & 15) * 4;
    u16x4 o;
#pragma unroll
    for (int i = 0; i < 4; ++i) o[i] = L[v4 + i][d];
    *(u16x4*)(Vt + (size_t)(b * ND + dt * 64 + d) * NTV + vt * 64 + v4) = o;
  }
}

// ------- kernel 1: keys = V @ W^T + bias, trunc-split, reg-prefetch pipeline -------
__global__ __launch_bounds__(256, 2) void k_keys(const float* __restrict__ V,
                                                 const float* __restrict__ W,
                                                 const float* __restrict__ bias,
                                                 unsigned int* __restrict__ kbuf) {
  int bid = blockIdx.x;
  int swz = (bid & 7) * 128 + (bid >> 3);
  int bm = swz >> 2, bn = swz & 3;
  int t = threadIdx.x, lane = t & 63, w = t >> 6;
  int wr = (w >> 1) * 64, wc = (w & 1) * 64;
  __shared__ __align__(16) unsigned char SMEM[73728];
  auto Ah = (unsigned short(*)[72])(SMEM);
  auto Al = (unsigned short(*)[72])(SMEM + 18432);
  auto Bh = (unsigned short(*)[72])(SMEM + 36864);
  auto Bl = (unsigned short(*)[72])(SMEM + 55296);
  f32x4 acc[4][4] = {};
  const int row0 = bm * 128, col0 = bn * 128;
  int srow = t >> 4, c4 = (t & 15) * 4;

  f32x4 vreg[8], wreg[8];
#pragma unroll
  for (int r = 0; r < 8; ++r) {
    vreg[r] = *(const f32x4*)(V + (size_t)(row0 + srow + r * 16) * ND + c4);
    wreg[r] = *(const f32x4*)(W + (size_t)(col0 + srow + r * 16) * ND + c4);
  }
  for (int k0 = 0; k0 < ND; k0 += 64) {
    __syncthreads();
#pragma unroll
    for (int r = 0; r < 8; ++r) {
      int row = srow + r * 16;
      u16x4 h, l;
#pragma unroll
      for (int j = 0; j < 4; ++j) {
        unsigned p = split2(vreg[r][j]);
        h[j] = (unsigned short)(p & 0xffffu); l[j] = (unsigned short)(p >> 16);
      }
      *(u16x4*)&Ah[row][c4] = h; *(u16x4*)&Al[row][c4] = l;
#pragma unroll
      for (int j = 0; j < 4; ++j) {
        unsigned p = split2(wreg[r][j]);
        h[j] = (unsigned short)(p & 0xffffu); l[j] = (unsigned short)(p >> 16);
      }
      *(u16x4*)&Bh[row][c4] = h; *(u16x4*)&Bl[row][c4] = l;
    }
    __syncthreads();
    if (k0 + 64 < ND) {
#pragma unroll
      for (int r = 0; r < 8; ++r) {
        vreg[r] = *(const f32x4*)(V + (size_t)(row0 + srow + r * 16) * ND + k0 + 64 + c4);
        wreg[r] = *(const f32x4*)(W + (size_t)(col0 + srow + r * 16) * ND + k0 + 64 + c4);
      }
    }
#pragma unroll
    for (int kk = 0; kk < 2; ++kk) {
      int kof = kk * 32 + ((lane >> 4) << 3);
      bf16x8 ah[4], al[4], bh[4], bl[4];
#pragma unroll
      for (int i = 0; i < 4; ++i) {
        int ra = wr + i * 16 + (lane & 15);
        ah[i] = *(const bf16x8*)&Ah[ra][kof];
        al[i] = *(const bf16x8*)&Al[ra][kof];
        int rb = wc + i * 16 + (lane & 15);
        bh[i] = *(const bf16x8*)&Bh[rb][kof];
        bl[i] = *(const bf16x8*)&Bl[rb][kof];
      }
#pragma unroll
      for (int i = 0; i < 4; ++i)
#pragma unroll
        for (int j = 0; j < 4; ++j) {
          acc[i][j] = mfma16(ah[i], bh[j], acc[i][j]);
          acc[i][j] = mfma16(ah[i], bl[j], acc[i][j]);
          acc[i][j] = mfma16(al[i], bh[j], acc[i][j]);
        }
    }
  }
  // epilogue: stage packed C-tile in LDS, coalesced writes
  __syncthreads();
  unsigned* CT = (unsigned*)SMEM;                    // 128 x 134 u32
#pragma unroll
  for (int j = 0; j < 4; ++j) {
    int col_l = wc + j * 16 + (lane & 15);
    float bj = bias[col0 + col_l];
#pragma unroll
    for (int i = 0; i < 4; ++i) {
      int rb_l = wr + i * 16 + ((lane >> 4) << 2);
#pragma unroll
      for (int r = 0; r < 4; ++r) CT[(rb_l + r) * 134 + col_l] = split2(acc[i][j][r] + bj);
    }
  }
  __syncthreads();
#pragma unroll
  for (int it = 0; it < 32; ++it) {
    int idx = it * 256 + t;
    int row = idx >> 6, c2 = idx & 63;
    *(u32x2*)(kbuf + (size_t)(row0 + row) * 1024 + col0 + c2 * 2) =
        *(const u32x2*)&CT[row * 134 + c2 * 2];
  }
}

// ------- kernel 2: scores GEMM + fused block-softmax -------
// writes e = exp(s - m_blk) bf16 in [b][q][v] layout (out1 row (b,q) second half) + partials.
__global__ __launch_bounds__(256, 2) void k_scores(const float* __restrict__ Q,
                                                   const unsigned int* __restrict__ kbuf,
                                                   unsigned short* __restrict__ ebase,
                                                   float2* __restrict__ partials) {
  int bid = blockIdx.x;
  int swz = (bid & 7) * 256 + (bid >> 3);
  int b = swz >> 6, rr2 = swz & 63, vt = rr2 >> 3, qt = rr2 & 7;
  int t = threadIdx.x, lane = t & 63, w = t >> 6, g = lane >> 4, l15 = lane & 15;
  int wr = (w >> 1) * 64, wc = (w & 1) * 64;
  __shared__ __align__(16) unsigned char SMEM[73728];
  auto Ah = (unsigned short(*)[72])(SMEM);
  auto Al = (unsigned short(*)[72])(SMEM + 18432);
  auto Bh = (unsigned short(*)[72])(SMEM + 36864);
  auto Bl = (unsigned short(*)[72])(SMEM + 55296);
  f32x4 acc[4][4] = {};
  const size_t qrow = (size_t)(b * NTQ + qt * 128);
  const size_t krow = (size_t)(b * NTV + vt * 128);
  int srow = t >> 4, c4 = (t & 15) * 4;

  f32x4 qreg[8]; u32x4 kreg[8];
#pragma unroll
  for (int r = 0; r < 8; ++r) {
    qreg[r] = *(const f32x4*)(Q + (qrow + srow + r * 16) * ND + c4);
    kreg[r] = *(const u32x4*)(kbuf + (krow + srow + r * 16) * 1024 + c4);
  }
  for (int k0 = 0; k0 < ND; k0 += 64) {
    __syncthreads();
#pragma unroll
    for (int r = 0; r < 8; ++r) {
      int row = srow + r * 16;
      u16x4 h, l;
#pragma unroll
      for (int j = 0; j < 4; ++j) {
        unsigned p = split2(qreg[r][j]);
        h[j] = (unsigned short)(p & 0xffffu); l[j] = (unsigned short)(p >> 16);
      }
      *(u16x4*)&Ah[row][c4] = h; *(u16x4*)&Al[row][c4] = l;
#pragma unroll
      for (int j = 0; j < 4; ++j) {
        h[j] = (unsigned short)(kreg[r][j] & 0xffffu);
        l[j] = (unsigned short)(kreg[r][j] >> 16);
      }
      *(u16x4*)&Bh[row][c4] = h; *(u16x4*)&Bl[row][c4] = l;
    }
    __syncthreads();
    if (k0 + 64 < ND) {
#pragma unroll
      for (int r = 0; r < 8; ++r) {
        qreg[r] = *(const f32x4*)(Q + (qrow + srow + r * 16) * ND + k0 + 64 + c4);
        kreg[r] = *(const u32x4*)(kbuf + (krow + srow + r * 16) * 1024 + k0 + 64 + c4);
      }
    }
#pragma unroll
    for (int kk = 0; kk < 2; ++kk) {
      int kof = kk * 32 + ((lane >> 4) << 3);
      bf16x8 ah[4], al[4], bh[4], bl[4];
#pragma unroll
      for (int i = 0; i < 4; ++i) {
        int ra = wr + i * 16 + (lane & 15);
        ah[i] = *(const bf16x8*)&Ah[ra][kof];
        al[i] = *(const bf16x8*)&Al[ra][kof];
        int rb = wc + i * 16 + (lane & 15);
        bh[i] = *(const bf16x8*)&Bh[rb][kof];
        bl[i] = *(const bf16x8*)&Bl[rb][kof];
      }
#pragma unroll
      for (int i = 0; i < 4; ++i)
#pragma unroll
        for (int j = 0; j < 4; ++j) {
          acc[i][j] = mfma16(ah[i], bh[j], acc[i][j]);
          acc[i][j] = mfma16(ah[i], bl[j], acc[i][j]);
          acc[i][j] = mfma16(al[i], bh[j], acc[i][j]);
        }
    }
  }
  // ---- fused block softmax: m over this block's 128 v per q; e tile bf16 [q][v]; partial (m,l) ----
  __syncthreads();
  auto E2 = (unsigned short(*)[136])(SMEM);     // [128 q][136] u16 = 34816 B
  float* Lm = (float*)(SMEM + 36864);           // [128][2] f32
  float* Ls = (float*)(SMEM + 37888);
#pragma unroll
  for (int i = 0; i < 4; ++i)
#pragma unroll
    for (int r = 0; r < 4; ++r) {
      float m = fmaxf(fmaxf(acc[i][0][r], acc[i][1][r]), fmaxf(acc[i][2][r], acc[i][3][r]));
#pragma unroll
      for (int msk = 1; msk < 16; msk <<= 1) m = fmaxf(m, __shfl_xor(m, msk));
      if (l15 == 0) Lm[(wr + i * 16 + g * 4 + r) * 2 + (w & 1)] = m;
    }
  __syncthreads();
#pragma unroll
  for (int i = 0; i < 4; ++i)
#pragma unroll
    for (int r = 0; r < 4; ++r) {
      int ql = wr + i * 16 + g * 4 + r;
      float mf = fmaxf(Lm[ql * 2], Lm[ql * 2 + 1]);
      float s = 0.f;
#pragma unroll
      for (int j = 0; j < 4; ++j) {
        float e = __expf(acc[i][j][r] - mf);
        s += e;
        E2[ql][wc + j * 16 + l15] = f2bf(e);     // q-major store
      }
#pragma unroll
      for (int msk = 1; msk < 16; msk <<= 1) s += __shfl_xor(s, msk);
      if (l15 == 0) Ls[ql * 2 + (w & 1)] = s;
    }
  __syncthreads();
  if (t < 128) {
    float mf = fmaxf(Lm[t * 2], Lm[t * 2 + 1]);
    float lf = Ls[t * 2] + Ls[t * 2 + 1];
    partials[(((size_t)(b * 8 + vt)) << 10) + qt * 128 + t] = make_float2(mf, lf);
  }
  // e rows q (128), 256B runs at v-column offset vt*128
#pragma unroll
  for (int it = 0; it < 8; ++it) {
    int idx = it * 256 + t;
    int row = idx >> 4, ch = idx & 15;
    *(u16x8*)(ebase + (size_t)(b * 1024 + qt * 128 + row) * 2048 + 1024 + vt * 128 + ch * 8) =
        *(const u16x8*)&E2[row][ch * 8];
  }
}

// ------- kernel 3: combine 8 partials per (b,q) -> global (M, 1/L) -------
__global__ __launch_bounds__(256) void k_combine(const float2* __restrict__ partials,
                                                 float2* __restrict__ stats) {
  int idx = blockIdx.x * 256 + threadIdx.x;   // 32768
  int b = idx >> 10, q = idx & 1023;
  float2 p[8];
  float M = -3.0e38f;
#pragma unroll
  for (int vt = 0; vt < 8; ++vt) {
    p[vt] = partials[(((size_t)(b * 8 + vt)) << 10) + q];
    M = fmaxf(M, p[vt].x);
  }
  float L = 0.f;
#pragma unroll
  for (int vt = 0; vt < 8; ++vt) L += p[vt].y * __expf(p[vt].x - M);
  stats[idx] = make_float2(M, 1.0f / L);
}

// ------- kernel 4: context = alpha @ V ; 128q x 128d tile GEMM over K=v -------
// A-tile: straight coalesced copy of e rows (q-major) with per-row scalar scale; B-tile: Vt rows.
__global__ __launch_bounds__(256, 3) void k_pv(const unsigned short* __restrict__ ebase,
                                               const unsigned short* __restrict__ Vt,
                                               const float2* __restrict__ stats,
                                               const float2* __restrict__ partials,
                                               float* __restrict__ out1) {
  int bid = blockIdx.x;
  int swz = (bid & 7) * 128 + (bid >> 3);        // 1024 blocks; (b,qt) pairs stay on one XCD
  int b = swz >> 5, qt = (swz >> 2) & 7, dt = swz & 3;
  int t = threadIdx.x, lane = t & 63, w = t >> 6;
  int l15 = lane & 15, g = lane >> 4;
  int wr = (w >> 1) * 64, wc = (w & 1) * 64;
  int q0 = qt * 128, d0 = dt * 128;
  __shared__ __align__(16) unsigned char SMEM[36864];
  auto Ae = (unsigned short(*)[72])(SMEM);           // [128 q][72]
  auto Bv = (unsigned short(*)[72])(SMEM + 18432);   // [128 d][72]
  f32x4 acc[4][4] = {};

  int srow = t >> 3, c8 = (t & 7) * 8;   // staging: rows srow+32k, 16B per thread
  float M4[4], iL4[4];
#pragma unroll
  for (int k = 0; k < 4; ++k) {
    float2 st = stats[b * NTQ + q0 + srow + 32 * k];
    M4[k] = st.x; iL4[k] = st.y;
  }
  u16x8 ereg[4], vreg[4];
#pragma unroll
  for (int k = 0; k < 4; ++k) {
    ereg[k] = *(const u16x8*)(ebase + (size_t)(b * 1024 + q0 + srow + 32 * k) * 2048 + 1024 + c8);
    vreg[k] = *(const u16x8*)(Vt + ((size_t)b * ND + d0 + srow + 32 * k) * NTV + c8);
  }
  float sck[4];
  for (int v0 = 0; v0 < NTV; v0 += 64) {
    if ((v0 & 127) == 0) {            // refresh per-row scale for this 128-v scores block
      int vt128 = v0 >> 7;
#pragma unroll
      for (int k = 0; k < 4; ++k) {
        float2 p = partials[(((size_t)(b * 8 + vt128)) << 10) + q0 + srow + 32 * k];
        sck[k] = __expf(p.x - M4[k]) * iL4[k];
      }
    }
    __syncthreads();
#pragma unroll
    for (int k = 0; k < 4; ++k) {
      int row = srow + 32 * k;
      u16x8 a;
#pragma unroll
      for (int m = 0; m < 8; ++m) a[m] = f2bf(bf2f(ereg[k][m]) * sck[k]);
      *(u16x8*)&Ae[row][c8] = a;
      *(u16x8*)&Bv[row][c8] = vreg[k];
    }
    if (v0 + 64 < NTV) {
#pragma unroll
      for (int k = 0; k < 4; ++k) {
        ereg[k] = *(const u16x8*)(ebase + (size_t)(b * 1024 + q0 + srow + 32 * k) * 2048 + 1024 + v0 + 64 + c8);
        vreg[k] = *(const u16x8*)(Vt + ((size_t)b * ND + d0 + srow + 32 * k) * NTV + v0 + 64 + c8);
      }
    }
    __syncthreads();
#pragma unroll
    for (int kk = 0; kk < 2; ++kk) {
      int kof = kk * 32 + g * 8;
      bf16x8 af[4], bfr[4];
#pragma unroll
      for (int i = 0; i < 4; ++i) af[i] = *(const bf16x8*)&Ae[wr + i * 16 + l15][kof];
#pragma unroll
      for (int j = 0; j < 4; ++j) bfr[j] = *(const bf16x8*)&Bv[wc + j * 16 + l15][kof];
#pragma unroll
      for (int i = 0; i < 4; ++i)
#pragma unroll
        for (int j = 0; j < 4; ++j) acc[i][j] = mfma16(af[i], bfr[j], acc[i][j]);
    }
  }
  // epilogue: context via LDS staging ([64][132] f32), two q-halves, 512B runs
  float* CT = (float*)SMEM;
#pragma unroll
  for (int h = 0; h < 2; ++h) {
    __syncthreads();
    if ((w >> 1) == h) {
#pragma unroll
      for (int i = 0; i < 4; ++i)
#pragma unroll
        for (int j = 0; j < 4; ++j) {
          int ql = i * 16 + g * 4;
          int dl = wc + j * 16 + l15;
#pragma unroll
          for (int r = 0; r < 4; ++r) CT[(ql + r) * 132 + dl] = acc[i][j][r];
        }
    }
    __syncthreads();
#pragma unroll
    for (int it = 0; it < 8; ++it) {
      int idx = it * 256 + t;
      int row = idx >> 5, c4 = idx & 31;
      *(f32x4*)(out1 + (size_t)(b * NTQ + q0 + h * 64 + row) * 1024 + d0 + c4 * 4) =
          *(const f32x4*)&CT[row * 132 + c4 * 4];
    }
  }
}

// ------- kernel 5: alpha = e*sc -> out2 (via swizzled LDS transpose) + fused Q-concat -------
// NOTE: ebase and out1 alias (same d_out region) -> no __restrict__ on them.
__global__ __launch_bounds__(256) void k_alpha(const unsigned short* ebase,
                                               const float* __restrict__ Q,
                                               const float2* __restrict__ stats,
                                               const float2* __restrict__ partials,
                                               float* __restrict__ out2,
                                               float* out1) {
  int bid = blockIdx.x;                       // 512
  int swz = (bid & 7) * 64 + (bid >> 3);
  int b = swz >> 4, qc = swz & 15;
  int q0 = qc * 64;
  int t = threadIdx.x;
  __shared__ float T[128][68];                // 34816 B; col XOR-swizzled by ((v>>3)&7)<<3
  int row = t >> 4, ch = t & 15;              // e-read roles: 16 threads per q-row
  float M4[4], iL4[4];
#pragma unroll
  for (int k = 0; k < 4; ++k) {
    float2 st = stats[b * NTQ + q0 + row + 16 * k];
    M4[k] = st.x; iL4[k] = st.y;
  }
  for (int vt = 0; vt < 8; ++vt) {
    __syncthreads();
#pragma unroll
    for (int k = 0; k < 4; ++k) {
      int r = row + 16 * k;                   // q-local 0..63
      float2 p = partials[(((size_t)(b * 8 + vt)) << 10) + q0 + r];
      float sc = __expf(p.x - M4[k]) * iL4[k];
      u16x8 ev = *(const u16x8*)(ebase + (size_t)(b * 1024 + q0 + r) * 2048 + 1024 + vt * 128 + ch * 8);
#pragma unroll
      for (int m = 0; m < 8; ++m) {
        int v = ch * 8 + m;
        T[v][r ^ (((v >> 3) & 7) << 3)] = bf2f(ev[m]) * sc;
      }
    }
    __syncthreads();
#pragma unroll
    for (int it = 0; it < 8; ++it) {
      int idx = it * 256 + t;
      int vr = idx >> 4, c4 = idx & 15;
      int cs = (c4 * 4) ^ (((vr >> 3) & 7) << 3);
      *(f32x4*)(out2 + ((size_t)(b * 1024) + vt * 128 + vr) * 1024 + q0 + c4 * 4) =
          *(const f32x4*)&T[vr][cs];
    }
  }
  __syncthreads();   // all e reads drained before overwriting with Q-concat
  // Q-concat: 64 rows x 512 cols = 8192 f32x4 chunks -> 32 iterations of 256 threads
#pragma unroll
  for (int k = 0; k < 32; ++k) {
    int idx = k * 256 + t;
    int r = idx >> 7, c4 = idx & 127;
    *(f32x4*)(out1 + (size_t)(b * 1024 + q0 + r) * 1024 + 512 + c4 * 4) =
        *(const f32x4*)(Q + (size_t)(b * 1024 + q0 + r) * 512 + c4 * 4);
  }
}

extern "C" void kernel_launch(void* const* d_in, const int* in_sizes, int n_in,
                              void* d_out, int out_size, void* d_ws, size_t ws_size,
                              hipStream_t stream) {
  const float* Q    = (const float*)d_in[0];
  const float* V    = (const float*)d_in[1];
  const float* W    = (const float*)d_in[2];
  const float* bias = (const float*)d_in[3];

  float* out1 = (float*)d_out;                                   // context_cat [B,TQ,2D]
  float* out2 = (float*)d_out + (size_t)NB * NTQ * (2 * ND);     // alignment_t [B,TV,TQ]

  unsigned short* Vt = (unsigned short*)d_ws;                    // bf16 [B,D,TV]  32MB
  float2* stats    = (float2*)((char*)d_ws + 33554432);          // 256KB
  float2* partials = (float2*)((char*)d_ws + 33554432 + 262144); // 2MB

  unsigned int* kbuf = (unsigned int*)out1;          // keys hi|lo packed: out1 row first-halves
  unsigned short* ebase = (unsigned short*)out1;     // e bf16 [b][q][v]: out1 row second-halves

  k_vt<<<dim3(16, 8, 32), 256, 0, stream>>>(V, Vt);
  k_keys<<<1024, 256, 0, stream>>>(V, W, bias, kbuf);
  k_scores<<<2048, 256, 0, stream>>>(Q, kbuf, ebase, partials);
  k_combine<<<128, 256, 0, stream>>>(partials, stats);
  k_pv<<<1024, 256, 0, stream>>>(ebase, Vt, stats, partials, out1);
  k_alpha<<<512, 256, 0, stream>>>(ebase, Q, stats, partials, out2, out1);
}